// Round 10
// baseline (259.124 us; speedup 1.0000x reference)
//
#include <hip/hip_runtime.h>

#define NB 4
#define CB 64
#define HB 256
#define WB 256
#define OB 18
#define HWB (HB*WB)
#define QUARTC 16
#define SLICEC 8
#define EPSV 1e-5f

__device__ __forceinline__ int reflect_idx(int i, int n) {
    if (i < 0) i = -i;
    if (i >= n) i = 2*n - 2 - i;
    return i;
}

// Transpose weights (18,64,3,3) -> wt[c][o][k] so the conv reads 162
// contiguous floats per input channel (block-uniform -> s_load path; r8
// showed LDS-staged weights are SLOWER — ds pipe costs more than s_load waits).
__global__ __launch_bounds__(256) void transpose_w_kernel(
    const float* __restrict__ w, float* __restrict__ wt)
{
    int i = blockIdx.x * 256 + threadIdx.x;
    if (i < OB*CB*9) {
        int o   = i / (CB*9);
        int rem = i - o*CB*9;
        int c   = rem / 9;
        int k   = rem - c*9;
        wt[c*OB*9 + o*9 + k] = w[i];
    }
}

// 16 reflect-padded tap offsets covering a 2x2 pixel quad (rows h,h+1 x
// cols w,w+1): tap rows h-1..h+2, cols w-1..w+2. Channel-invariant.
#define MAKE_OFFS16(h, w) do {                                         \
    int _ro[4], _co[4];                                                \
    _Pragma("unroll")                                                  \
    for (int _d = 0; _d < 4; ++_d) {                                   \
        _ro[_d] = reflect_idx((h) - 1 + _d, HB) * WB;                  \
        _co[_d] = reflect_idx((w) - 1 + _d, WB);                       \
    }                                                                  \
    _Pragma("unroll")                                                  \
    for (int _dy = 0; _dy < 4; ++_dy)                                  \
        _Pragma("unroll")                                              \
        for (int _dx = 0; _dx < 4; ++_dx)                              \
            offs[_dy*4+_dx] = _ro[_dy] + _co[_dx];                     \
} while (0)

// Kernel 1: 3x3x(16 of 64)->18 conv + per-block sum/sumsq partials.
// Proven r9 inner body (direct tap loads, scalar uniform weights, 2x2 quad);
// channel split widened to 4-way (z=16) -> 1024 blocks = 4 blk/CU = 16
// waves/CU, restoring the TLP that r9's 4px quad gave up (r9: 2 blk/CU).
__global__ __launch_bounds__(256) void conv_stats_kernel(
    const float* __restrict__ y, const float* __restrict__ wt,
    float* __restrict__ sigma0, float* __restrict__ sigma1,
    float* __restrict__ sigma2, float* __restrict__ sigma3,
    float* __restrict__ psum, float* __restrict__ psq)
{
    __shared__ float red[4][36];
    const int tid = threadIdx.x;
    const int tx = tid & 15, ty = tid >> 4;
    const int bx = blockIdx.x, by = blockIdx.y;
    const int n = blockIdx.z >> 2, quarter = blockIdx.z & 3;
    const int h = by*32 + 2*ty;                    // quad rows h,h+1
    const int w = bx*32 + 2*tx;                    // quad cols w,w+1

    int offs[16];
    MAKE_OFFS16(h, w);

    const float* ybase = y + ((size_t)n*CB + quarter*QUARTC)*HWB;
    float* const sgs[4] = {sigma0, sigma1, sigma2, sigma3};
    float* const sg = sgs[quarter];

    float acc[4][OB];                              // [jv*2+jh][o]
#pragma unroll
    for (int j = 0; j < 4; ++j)
#pragma unroll
        for (int o = 0; o < OB; ++o) acc[j][o] = 0.f;

#pragma unroll 2
    for (int c = 0; c < QUARTC; ++c) {
        const float* p = ybase + (size_t)c*HWB;
        float v[16];
#pragma unroll
        for (int k = 0; k < 16; ++k) v[k] = p[offs[k]];
        const float* wp = wt + (quarter*QUARTC + c)*162;   // uniform -> s_load
#pragma unroll
        for (int o = 0; o < OB; ++o)
#pragma unroll
            for (int dy = 0; dy < 3; ++dy)
#pragma unroll
                for (int dx = 0; dx < 3; ++dx) {
                    const float w_ = wp[o*9 + dy*3 + dx];
                    acc[0][o] = fmaf(v[dy*4 + dx],       w_, acc[0][o]);
                    acc[1][o] = fmaf(v[dy*4 + dx + 1],   w_, acc[1][o]);
                    acc[2][o] = fmaf(v[(dy+1)*4 + dx],   w_, acc[2][o]);
                    acc[3][o] = fmaf(v[(dy+1)*4 + dx+1], w_, acc[3][o]);
                }
    }

    const int q = h*WB + w;
#pragma unroll
    for (int o = 0; o < OB; ++o) {
        const size_t b = ((size_t)n*OB + o)*HWB + q;
        *(float2*)(sg + b)      = make_float2(acc[0][o], acc[1][o]);
        *(float2*)(sg + b + WB) = make_float2(acc[2][o], acc[3][o]);
    }

    const int lane = tid & 63, wv = tid >> 6;
#pragma unroll
    for (int o = 0; o < OB; ++o) {
        float s  = acc[0][o] + acc[1][o] + acc[2][o] + acc[3][o];
        float s2 = acc[0][o]*acc[0][o] + acc[1][o]*acc[1][o]
                 + acc[2][o]*acc[2][o] + acc[3][o]*acc[3][o];
        for (int off = 32; off > 0; off >>= 1) {
            s  += __shfl_down(s,  off, 64);
            s2 += __shfl_down(s2, off, 64);
        }
        if (lane == 0) { red[wv][o] = s; red[wv][o + OB] = s2; }
    }
    __syncthreads();
    if (tid < 36) {
        float t = red[0][tid] + red[1][tid] + red[2][tid] + red[3][tid];
        const int bid = ((n*4 + quarter)*8 + by)*8 + bx;   // 0..1023
        if (tid < OB) psum[tid*1024 + bid] = t;
        else          psq[(tid-OB)*1024 + bid] = t;
    }
}

// Kernel 2: reduce 1024 partials per channel -> fused scale/shift
__global__ __launch_bounds__(256) void stats_kernel(
    const float* __restrict__ psum, const float* __restrict__ psq,
    const float* __restrict__ gamma, const float* __restrict__ beta,
    float* __restrict__ scale, float* __restrict__ shift)
{
    const int o = blockIdx.x;
    const int t = threadIdx.x;
    float s = 0.f, s2 = 0.f;
#pragma unroll
    for (int i = 0; i < 4; ++i) {
        s  += psum[o*1024 + t + i*256];
        s2 += psq [o*1024 + t + i*256];
    }
    for (int off = 32; off > 0; off >>= 1) {
        s  += __shfl_down(s,  off, 64);
        s2 += __shfl_down(s2, off, 64);
    }
    __shared__ float red[8];
    const int lane = t & 63, wv = t >> 6;
    if (lane == 0) { red[wv] = s; red[wv + 4] = s2; }
    __syncthreads();
    if (t == 0) {
        float S  = red[0] + red[1] + red[2] + red[3];
        float SS = red[4] + red[5] + red[6] + red[7];
        const float cnt = (float)(NB * HWB);
        float mean = S / cnt;
        float var  = SS / cnt - mean*mean;
        float sc = gamma[o] * rsqrtf(var + EPSV);
        scale[o] = sc;
        shift[o] = beta[o] - mean * sc;
    }
}

// Kernel 2.5: normalize + softmax over 18 -> v_map (a required output; the
// apply kernel re-reads it so each apply block only needs its group's 9 rows).
__global__ __launch_bounds__(256) void softmax_vmap_kernel(
    const float* __restrict__ sigma0, const float* __restrict__ sigma1,
    const float* __restrict__ sigma2, const float* __restrict__ sigma3,
    const float* __restrict__ scale, const float* __restrict__ shift,
    float* __restrict__ vmap)
{
    const int n = blockIdx.y;
    const int q = blockIdx.x * 256 + threadIdx.x;
    float z[OB];
#pragma unroll
    for (int o = 0; o < OB; ++o) {
        const size_t idx = ((size_t)n*OB + o)*HWB + q;
        z[o] = fmaf((sigma0[idx] + sigma1[idx]) + (sigma2[idx] + sigma3[idx]),
                    scale[o], shift[o]);
    }
    float m = z[0];
#pragma unroll
    for (int o = 1; o < OB; ++o) m = fmaxf(m, z[o]);
    float sum = 0.f;
#pragma unroll
    for (int o = 0; o < OB; ++o) { z[o] = __expf(z[o] - m); sum += z[o]; }
    const float rs = 1.f / sum;
#pragma unroll
    for (int o = 0; o < OB; ++o)
        vmap[((size_t)n*OB + o)*HWB + q] = z[o] * rs;
}

// Kernel 3: adaptive filter, direct-load, 2x2 quad per thread. Channel split
// widened to 8-way (z=32, 8 ch/block -> 2048 blocks = 8 blk/CU): this kernel
// is memory-latency-bound (9 strided taps per px, little compute) and needs
// wave contexts, not ILP. Slice stays inside one softmax group (slice>>2).
__global__ __launch_bounds__(256) void apply_kernel(
    const float* __restrict__ y, const float* __restrict__ vmap,
    float* __restrict__ out)
{
    const int tid = threadIdx.x;
    const int tx = tid & 15, ty = tid >> 4;
    const int bx = blockIdx.x, by = blockIdx.y;
    const int n = blockIdx.z >> 3, slice = blockIdx.z & 7;
    const int half = slice >> 2;                   // softmax group
    const int h = by*32 + 2*ty;
    const int w = bx*32 + 2*tx;
    const int q = h*WB + w;

    int offs[16];
    MAKE_OFFS16(h, w);

    const float* ybase = y + ((size_t)n*CB + slice*SLICEC)*HWB;

    float2 z0[9], z1[9];                           // per-pixel filter weights
#pragma unroll
    for (int k = 0; k < 9; ++k) {
        const size_t b = ((size_t)n*OB + half*9 + k)*HWB + q;
        z0[k] = *(const float2*)(vmap + b);
        z1[k] = *(const float2*)(vmap + b + WB);
    }

    float* obase = out + ((size_t)n*CB + slice*SLICEC)*HWB;

#pragma unroll 4
    for (int c = 0; c < SLICEC; ++c) {
        const float* p = ybase + (size_t)c*HWB;
        float v[16];
#pragma unroll
        for (int k = 0; k < 16; ++k) v[k] = p[offs[k]];
        float a00 = 0.f, a01 = 0.f, a10 = 0.f, a11 = 0.f;
#pragma unroll
        for (int dy = 0; dy < 3; ++dy)
#pragma unroll
            for (int dx = 0; dx < 3; ++dx) {
                const int k = dy*3 + dx;
                a00 = fmaf(v[dy*4 + dx],       z0[k].x, a00);
                a01 = fmaf(v[dy*4 + dx + 1],   z0[k].y, a01);
                a10 = fmaf(v[(dy+1)*4 + dx],   z1[k].x, a10);
                a11 = fmaf(v[(dy+1)*4 + dx+1], z1[k].y, a11);
            }
        const size_t b = (size_t)c*HWB + q;
        *(float2*)(obase + b)      = make_float2(a00, a01);
        *(float2*)(obase + b + WB) = make_float2(a10, a11);
    }
}

extern "C" void kernel_launch(void* const* d_in, const int* in_sizes, int n_in,
                              void* d_out, int out_size, void* d_ws, size_t ws_size,
                              hipStream_t stream) {
    const float* y     = (const float*)d_in[0];
    const float* w     = (const float*)d_in[1];
    const float* gamma = (const float*)d_in[2];
    const float* beta  = (const float*)d_in[3];
    float* out = (float*)d_out;

    const size_t SSZ = (size_t)NB*OB*HWB;         // one sigma buffer (4.72M floats)

    float* sigma0 = (float*)d_ws;                 // in workspace
    float* wt     = sigma0 + SSZ;                 // 10368
    float* psum   = wt + OB*CB*9;                 // 18*1024
    float* psq    = psum + OB*1024;               // 18*1024
    float* scale  = psq  + OB*1024;               // 18
    float* shift  = scale + OB;                   // 18

    // out's 64-channel region (16.78M floats) is dead until apply -> holds
    // sigma quarters 1..3 (3 x 4.72M = 14.16M floats).
    float* sigma1 = out;
    float* sigma2 = out + SSZ;
    float* sigma3 = out + 2*SSZ;
    float* vmap   = out + (size_t)NB*CB*HWB;

    dim3 block(256);
    transpose_w_kernel<<<dim3((OB*CB*9 + 255)/256), block, 0, stream>>>(w, wt);
    conv_stats_kernel<<<dim3(8,8,16), block, 0, stream>>>(y, wt, sigma0, sigma1, sigma2, sigma3, psum, psq);
    stats_kernel<<<dim3(OB), block, 0, stream>>>(psum, psq, gamma, beta, scale, shift);
    softmax_vmap_kernel<<<dim3(HWB/256, NB), block, 0, stream>>>(sigma0, sigma1, sigma2, sigma3, scale, shift, vmap);
    apply_kernel<<<dim3(8,8,32), block, 0, stream>>>(y, vmap, out);
}

// Round 11
// 248.987 us; speedup vs baseline: 1.0407x; 1.0407x over previous
//
#include <hip/hip_runtime.h>

#define NB 4
#define CB 64
#define HB 256
#define WB 256
#define OB 18
#define HWB (HB*WB)
#define HALFC 32
#define EPSV 1e-5f

__device__ __forceinline__ int reflect_idx(int i, int n) {
    if (i < 0) i = -i;
    if (i >= n) i = 2*n - 2 - i;
    return i;
}

// Transpose weights (18,64,3,3) -> wt[c][o][k] so the conv reads 162
// contiguous floats per input channel (block-uniform -> s_load path).
__global__ __launch_bounds__(256) void transpose_w_kernel(
    const float* __restrict__ w, float* __restrict__ wt)
{
    int i = blockIdx.x * 256 + threadIdx.x;
    if (i < OB*CB*9) {
        int o   = i / (CB*9);
        int rem = i - o*CB*9;
        int c   = rem / 9;
        int k   = rem - c*9;
        wt[c*OB*9 + o*9 + k] = w[i];
    }
}

// 16 reflect-padded tap offsets covering a 2x2 pixel quad (rows h,h+1 x
// cols w,w+1): tap rows h-1..h+2, cols w-1..w+2. Channel-invariant.
#define MAKE_OFFS16(h, w) do {                                         \
    int _ro[4], _co[4];                                                \
    _Pragma("unroll")                                                  \
    for (int _d = 0; _d < 4; ++_d) {                                   \
        _ro[_d] = reflect_idx((h) - 1 + _d, HB) * WB;                  \
        _co[_d] = reflect_idx((w) - 1 + _d, WB);                       \
    }                                                                  \
    _Pragma("unroll")                                                  \
    for (int _dy = 0; _dy < 4; ++_dy)                                  \
        _Pragma("unroll")                                              \
        for (int _dx = 0; _dx < 4; ++_dx)                              \
            offs[_dy*4+_dx] = _ro[_dy] + _co[_dx];                     \
} while (0)

// Kernel 1 (r9 exact — best measured 88-90us): 3x3x(32 of 64)->18 conv +
// per-block sum/sumsq partials. Direct tap loads, scalar uniform weights,
// 2x2 quad/thread, 2-way channel split.
__global__ __launch_bounds__(256) void conv_stats_kernel(
    const float* __restrict__ y, const float* __restrict__ wt,
    float* __restrict__ sigma0, float* __restrict__ sigma1,
    float* __restrict__ psum, float* __restrict__ psq)
{
    __shared__ float red[4][36];
    const int tid = threadIdx.x;
    const int tx = tid & 15, ty = tid >> 4;
    const int bx = blockIdx.x, by = blockIdx.y;
    const int n = blockIdx.z >> 1, half = blockIdx.z & 1;
    const int h = by*32 + 2*ty;
    const int w = bx*32 + 2*tx;

    int offs[16];
    MAKE_OFFS16(h, w);

    const float* ybase = y + ((size_t)n*CB + half*HALFC)*HWB;
    float* const sg = half ? sigma1 : sigma0;

    float acc[4][OB];
#pragma unroll
    for (int j = 0; j < 4; ++j)
#pragma unroll
        for (int o = 0; o < OB; ++o) acc[j][o] = 0.f;

#pragma unroll 2
    for (int c = 0; c < HALFC; ++c) {
        const float* p = ybase + (size_t)c*HWB;
        float v[16];
#pragma unroll
        for (int k = 0; k < 16; ++k) v[k] = p[offs[k]];
        const float* wp = wt + (half*HALFC + c)*162;   // uniform -> s_load
#pragma unroll
        for (int o = 0; o < OB; ++o)
#pragma unroll
            for (int dy = 0; dy < 3; ++dy)
#pragma unroll
                for (int dx = 0; dx < 3; ++dx) {
                    const float w_ = wp[o*9 + dy*3 + dx];
                    acc[0][o] = fmaf(v[dy*4 + dx],       w_, acc[0][o]);
                    acc[1][o] = fmaf(v[dy*4 + dx + 1],   w_, acc[1][o]);
                    acc[2][o] = fmaf(v[(dy+1)*4 + dx],   w_, acc[2][o]);
                    acc[3][o] = fmaf(v[(dy+1)*4 + dx+1], w_, acc[3][o]);
                }
    }

    const int q = h*WB + w;
#pragma unroll
    for (int o = 0; o < OB; ++o) {
        const size_t b = ((size_t)n*OB + o)*HWB + q;
        *(float2*)(sg + b)      = make_float2(acc[0][o], acc[1][o]);
        *(float2*)(sg + b + WB) = make_float2(acc[2][o], acc[3][o]);
    }

    const int lane = tid & 63, wv = tid >> 6;
#pragma unroll
    for (int o = 0; o < OB; ++o) {
        float s  = acc[0][o] + acc[1][o] + acc[2][o] + acc[3][o];
        float s2 = acc[0][o]*acc[0][o] + acc[1][o]*acc[1][o]
                 + acc[2][o]*acc[2][o] + acc[3][o]*acc[3][o];
        for (int off = 32; off > 0; off >>= 1) {
            s  += __shfl_down(s,  off, 64);
            s2 += __shfl_down(s2, off, 64);
        }
        if (lane == 0) { red[wv][o] = s; red[wv][o + OB] = s2; }
    }
    __syncthreads();
    if (tid < 36) {
        float t = red[0][tid] + red[1][tid] + red[2][tid] + red[3][tid];
        const int bid = ((n*2 + half)*8 + by)*8 + bx;   // 0..511
        if (tid < OB) psum[tid*512 + bid] = t;
        else          psq[(tid-OB)*512 + bid] = t;
    }
}

// Kernel 2: reduce 512 partials per channel -> fused scale/shift
__global__ __launch_bounds__(256) void stats_kernel(
    const float* __restrict__ psum, const float* __restrict__ psq,
    const float* __restrict__ gamma, const float* __restrict__ beta,
    float* __restrict__ scale, float* __restrict__ shift)
{
    const int o = blockIdx.x;
    const int t = threadIdx.x;
    float s  = psum[o*512 + t] + psum[o*512 + t + 256];
    float s2 = psq [o*512 + t] + psq [o*512 + t + 256];
    for (int off = 32; off > 0; off >>= 1) {
        s  += __shfl_down(s,  off, 64);
        s2 += __shfl_down(s2, off, 64);
    }
    __shared__ float red[8];
    const int lane = t & 63, wv = t >> 6;
    if (lane == 0) { red[wv] = s; red[wv + 4] = s2; }
    __syncthreads();
    if (t == 0) {
        float S  = red[0] + red[1] + red[2] + red[3];
        float SS = red[4] + red[5] + red[6] + red[7];
        const float cnt = (float)(NB * HWB);
        float mean = S / cnt;
        float var  = SS / cnt - mean*mean;
        float sc = gamma[o] * rsqrtf(var + EPSV);
        scale[o] = sc;
        shift[o] = beta[o] - mean * sc;
    }
}

// Kernel 2.5: normalize + softmax over 18 -> v_map. 4 px/thread via float4:
// same bytes, 1/4 the VMEM instructions (this kernel is issue-bound).
__global__ __launch_bounds__(256) void softmax_vmap_kernel(
    const float* __restrict__ sigma0, const float* __restrict__ sigma1,
    const float* __restrict__ scale, const float* __restrict__ shift,
    float* __restrict__ vmap)
{
    const int n = blockIdx.y;
    const int q = (blockIdx.x * 256 + threadIdx.x) * 4;
    float4 z[OB];
#pragma unroll
    for (int o = 0; o < OB; ++o) {
        const size_t idx = ((size_t)n*OB + o)*HWB + q;
        const float4 a = *(const float4*)(sigma0 + idx);
        const float4 b = *(const float4*)(sigma1 + idx);
        const float sc = scale[o], sh = shift[o];
        z[o].x = fmaf(a.x + b.x, sc, sh);
        z[o].y = fmaf(a.y + b.y, sc, sh);
        z[o].z = fmaf(a.z + b.z, sc, sh);
        z[o].w = fmaf(a.w + b.w, sc, sh);
    }
    float4 m = z[0];
#pragma unroll
    for (int o = 1; o < OB; ++o) {
        m.x = fmaxf(m.x, z[o].x); m.y = fmaxf(m.y, z[o].y);
        m.z = fmaxf(m.z, z[o].z); m.w = fmaxf(m.w, z[o].w);
    }
    float4 sum = make_float4(0.f, 0.f, 0.f, 0.f);
#pragma unroll
    for (int o = 0; o < OB; ++o) {
        z[o].x = __expf(z[o].x - m.x); sum.x += z[o].x;
        z[o].y = __expf(z[o].y - m.y); sum.y += z[o].y;
        z[o].z = __expf(z[o].z - m.z); sum.z += z[o].z;
        z[o].w = __expf(z[o].w - m.w); sum.w += z[o].w;
    }
    const float4 rs = make_float4(1.f/sum.x, 1.f/sum.y, 1.f/sum.z, 1.f/sum.w);
#pragma unroll
    for (int o = 0; o < OB; ++o) {
        float4 r;
        r.x = z[o].x * rs.x; r.y = z[o].y * rs.y;
        r.z = z[o].z * rs.z; r.w = z[o].w * rs.w;
        *(float4*)(vmap + ((size_t)n*OB + o)*HWB + q) = r;
    }
}

// Kernel 3: adaptive filter, 1x4 horizontal px/thread at 16B-aligned w:
// per channel-row one float4 + 2 edge scalars (9 loads/channel for 4 px,
// 2.25/px vs 4/px before), float4 stores, z as 9 float4 loads.
// VMEM instr/thread: 594 -> 329. All indexing static (rule #20).
__global__ __launch_bounds__(256) void apply_kernel(
    const float* __restrict__ y, const float* __restrict__ vmap,
    float* __restrict__ out)
{
    const int tid = threadIdx.x;
    const int tx = tid & 15, ty = tid >> 4;
    const int bx = blockIdx.x, by = blockIdx.y;
    const int n = blockIdx.z >> 1, half = blockIdx.z & 1;  // group g == half
    const int h = by*16 + ty;          // 0..255
    const int w = bx*64 + 4*tx;        // 0..252, 16B-aligned
    const int q = h*WB + w;

    const int r0 = reflect_idx(h-1, HB)*WB;
    const int r1 = h*WB;
    const int r2 = reflect_idx(h+1, HB)*WB;
    const int wm1 = reflect_idx(w-1, WB);
    const int wp4 = reflect_idx(w+4, WB);

    const float* ybase = y + ((size_t)n*CB + half*HALFC)*HWB;

    float4 z4[9];                      // tap k weights for the 4 pixels
#pragma unroll
    for (int k = 0; k < 9; ++k)
        z4[k] = *(const float4*)(vmap + ((size_t)n*OB + half*9 + k)*HWB + q);

    float* obase = out + ((size_t)n*CB + half*HALFC)*HWB;

#pragma unroll 2
    for (int c = 0; c < HALFC; ++c) {
        const float* p = ybase + (size_t)c*HWB;
        float a0 = 0.f, a1 = 0.f, a2 = 0.f, a3 = 0.f;
        const int rr[3] = {r0, r1, r2};
#pragma unroll
        for (int dy = 0; dy < 3; ++dy) {
            const int r = rr[dy];
            const float4 mv = *(const float4*)(p + r + w);
            float t[6];
            t[0] = p[r + wm1];
            t[1] = mv.x; t[2] = mv.y; t[3] = mv.z; t[4] = mv.w;
            t[5] = p[r + wp4];
#pragma unroll
            for (int dx = 0; dx < 3; ++dx) {
                const int k = dy*3 + dx;
                a0 = fmaf(t[0 + dx], z4[k].x, a0);
                a1 = fmaf(t[1 + dx], z4[k].y, a1);
                a2 = fmaf(t[2 + dx], z4[k].z, a2);
                a3 = fmaf(t[3 + dx], z4[k].w, a3);
            }
        }
        *(float4*)(obase + (size_t)c*HWB + q) = make_float4(a0, a1, a2, a3);
    }
}

extern "C" void kernel_launch(void* const* d_in, const int* in_sizes, int n_in,
                              void* d_out, int out_size, void* d_ws, size_t ws_size,
                              hipStream_t stream) {
    const float* y     = (const float*)d_in[0];
    const float* w     = (const float*)d_in[1];
    const float* gamma = (const float*)d_in[2];
    const float* beta  = (const float*)d_in[3];
    float* out = (float*)d_out;

    float* sigma0 = (float*)d_ws;                 // 4*18*65536 floats
    float* wt     = sigma0 + (size_t)NB*OB*HWB;   // 10368
    float* psum   = wt + OB*CB*9;                 // 18*512
    float* psq    = psum + OB*512;                // 18*512
    float* scale  = psq  + OB*512;                // 18
    float* shift  = scale + OB;                   // 18

    float* sigma1 = out;                          // out region is dead until apply
    float* vmap   = out + (size_t)NB*CB*HWB;

    dim3 block(256);
    transpose_w_kernel<<<dim3((OB*CB*9 + 255)/256), block, 0, stream>>>(w, wt);
    conv_stats_kernel<<<dim3(8,8,8), block, 0, stream>>>(y, wt, sigma0, sigma1, psum, psq);
    stats_kernel<<<dim3(OB), block, 0, stream>>>(psum, psq, gamma, beta, scale, shift);
    softmax_vmap_kernel<<<dim3(HWB/1024, NB), block, 0, stream>>>(sigma0, sigma1, scale, shift, vmap);
    apply_kernel<<<dim3(4,16,8), block, 0, stream>>>(y, vmap, out);
}